// Round 1
// baseline (400.248 us; speedup 1.0000x reference)
//
#include <hip/hip_runtime.h>
#include <math.h>

// AutoregressiveFlowLayer on MI355X — round 1: fp32 VALU, LDS-resident masked weights.
//
// Shapes: B=8192, D=1024, R=32, RMAX=32, H1=H2=128, O=64.
// FLOPs ~15 GF -> fp32 VALU floor ~96 us (no fp32 MFMA on CDNA4).
// Block = 256 thr, 1 block/CU (152 KB LDS). Grid = 32 r * 16 slabs = 512 blocks,
// each block: stage masked W1/W2/Wout in LDS once, then 16 tiles of 32 rows.

#define RR    32
#define DD    1024
#define RMAXX 32
#define HH    128
#define OO    64
#define BB    8192

#define TROWS 32            // batch rows per tile
#define TILES_PER_BLOCK 16
#define BLOCKS_PER_R 16     // 16 blocks * 16 tiles * 32 rows = 8192 rows

#define XG_S 36             // xg LDS row stride (floats): 16B-aligned, 4r%32 distinct quads
#define H_S  132            // h1/h2 LDS row stride: 16B-aligned, 4r%32 distinct quads

// Phase 1/2: 4 rows x 4 cols per thread.
// cg = tid>>3 (0..31) -> cols 4cg..4cg+3  (waves own disjoint col ranges: W read once/CU)
// rg = tid&7  (0..7)  -> rows rg, rg+8, rg+16, rg+24 (interleave-8: distinct bank quads)
template<int K, int AS>
__device__ __forceinline__ void gemm_relu_tile(const float* __restrict__ a_lds,
                                               const float* __restrict__ w_lds,
                                               float* __restrict__ o_lds,
                                               int tid)
{
    const int cg = tid >> 3;
    const int rg = tid & 7;
    const int c0 = cg * 4;
    float acc[4][4] = {};
#pragma unroll 8
    for (int k0 = 0; k0 < K; k0 += 4) {
        float4 a[4], w[4];
#pragma unroll
        for (int i = 0; i < 4; ++i)
            a[i] = *reinterpret_cast<const float4*>(&a_lds[(rg + 8 * i) * AS + k0]);
#pragma unroll
        for (int kk = 0; kk < 4; ++kk)
            w[kk] = *reinterpret_cast<const float4*>(&w_lds[(k0 + kk) * HH + c0]);
#pragma unroll
        for (int i = 0; i < 4; ++i) {
            const float* af = reinterpret_cast<const float*>(&a[i]);
#pragma unroll
            for (int kk = 0; kk < 4; ++kk) {
                const float* wf = reinterpret_cast<const float*>(&w[kk]);
#pragma unroll
                for (int j = 0; j < 4; ++j)
                    acc[i][j] = fmaf(af[kk], wf[j], acc[i][j]);
            }
        }
    }
#pragma unroll
    for (int i = 0; i < 4; ++i) {
        float4 o;
        o.x = fmaxf(acc[i][0], 0.f);
        o.y = fmaxf(acc[i][1], 0.f);
        o.z = fmaxf(acc[i][2], 0.f);
        o.w = fmaxf(acc[i][3], 0.f);
        *reinterpret_cast<float4*>(&o_lds[(rg + 8 * i) * H_S + c0]) = o;
    }
}

__global__ __launch_bounds__(256, 1)
void made_flow_kernel(const float* __restrict__ inputs,
                      const float* __restrict__ W1,
                      const float* __restrict__ W2,
                      const float* __restrict__ Wout,
                      const int* __restrict__ idx,
                      const int* __restrict__ valid,
                      const int* __restrict__ M1,
                      const int* __restrict__ M2,
                      const int* __restrict__ Mout,
                      float* __restrict__ out)
{
    __shared__ float w1s[RMAXX * HH];    // 16 KB
    __shared__ float w2s[HH * HH];       // 64 KB
    __shared__ float wouts[HH * OO];     // 32 KB
    __shared__ float xgs[TROWS * XG_S];  // 4.5 KB
    __shared__ float h1s[TROWS * H_S];   // 16.5 KB
    __shared__ float h2s[TROWS * H_S];   // 16.5 KB
    __shared__ float red[TROWS * 16];    // 2 KB
    __shared__ int   idx_s[RMAXX];
    __shared__ float v_s[RMAXX];

    const int tid = threadIdx.x;
    const int r   = blockIdx.x / BLOCKS_PER_R;
    const int rb  = blockIdx.x % BLOCKS_PER_R;

    // ---- stage masked weights (once per block) ----
    {
        const float4* wv = reinterpret_cast<const float4*>(W1 + r * RMAXX * HH);
        const int4*   mv = reinterpret_cast<const int4*>(M1 + r * RMAXX * HH);
        for (int i = tid; i < RMAXX * HH / 4; i += 256) {
            float4 w = wv[i]; int4 m = mv[i];
            w.x = m.x ? w.x : 0.f; w.y = m.y ? w.y : 0.f;
            w.z = m.z ? w.z : 0.f; w.w = m.w ? w.w : 0.f;
            *reinterpret_cast<float4*>(&w1s[i * 4]) = w;
        }
    }
    {
        const float4* wv = reinterpret_cast<const float4*>(W2 + r * HH * HH);
        const int4*   mv = reinterpret_cast<const int4*>(M2 + r * HH * HH);
        for (int i = tid; i < HH * HH / 4; i += 256) {
            float4 w = wv[i]; int4 m = mv[i];
            w.x = m.x ? w.x : 0.f; w.y = m.y ? w.y : 0.f;
            w.z = m.z ? w.z : 0.f; w.w = m.w ? w.w : 0.f;
            *reinterpret_cast<float4*>(&w2s[i * 4]) = w;
        }
    }
    {
        const float4* wv = reinterpret_cast<const float4*>(Wout + r * HH * OO);
        const int4*   mv = reinterpret_cast<const int4*>(Mout + r * HH * OO);
        for (int i = tid; i < HH * OO / 4; i += 256) {
            float4 w = wv[i]; int4 m = mv[i];
            w.x = m.x ? w.x : 0.f; w.y = m.y ? w.y : 0.f;
            w.z = m.z ? w.z : 0.f; w.w = m.w ? w.w : 0.f;
            *reinterpret_cast<float4*>(&wouts[i * 4]) = w;
        }
    }
    if (tid < RMAXX) {
        idx_s[tid] = idx[r * RMAXX + tid];
        v_s[tid]   = valid[r * RMAXX + tid] ? 1.f : 0.f;
    }
    __syncthreads();

    for (int t = 0; t < TILES_PER_BLOCK; ++t) {
        const int row0 = (rb * TILES_PER_BLOCK + t) * TROWS;

        // ---- gather: xg[row][j] = inputs[b, idx[r][j]] * valid[r][j] ----
        {
            const int row = tid >> 3;
            const int j0  = (tid & 7) * 4;
            const int base = (row0 + row) * DD;
#pragma unroll
            for (int u = 0; u < 4; ++u) {
                const int j = j0 + u;
                xgs[row * XG_S + j] = inputs[base + idx_s[j]] * v_s[j];
            }
        }
        __syncthreads();

        // ---- phase 1: h1 = relu(xg @ W1m)  (K=32) ----
        gemm_relu_tile<RMAXX, XG_S>(xgs, w1s, h1s, tid);
        __syncthreads();

        // ---- phase 2: h2 = relu(h1 @ W2m)  (K=128) ----
        gemm_relu_tile<HH, H_S>(h1s, w2s, h2s, tid);
        __syncthreads();

        // ---- phase 3: out = h2 @ Woutm (K=128), then log-lik epilogue ----
        {
            const int cg3 = tid >> 4;      // 0..15 -> cols 4cg3..4cg3+3 (2 j's)
            const int rg3 = tid & 15;      // rows rg3, rg3+16
            const int c0  = cg3 * 4;
            float acc[2][4] = {};
#pragma unroll 8
            for (int k0 = 0; k0 < HH; k0 += 4) {
                float4 a[2], w[4];
#pragma unroll
                for (int i = 0; i < 2; ++i)
                    a[i] = *reinterpret_cast<const float4*>(&h2s[(rg3 + 16 * i) * H_S + k0]);
#pragma unroll
                for (int kk = 0; kk < 4; ++kk)
                    w[kk] = *reinterpret_cast<const float4*>(&wouts[(k0 + kk) * OO + c0]);
#pragma unroll
                for (int i = 0; i < 2; ++i) {
                    const float* af = reinterpret_cast<const float*>(&a[i]);
#pragma unroll
                    for (int kk = 0; kk < 4; ++kk) {
                        const float* wf = reinterpret_cast<const float*>(&w[kk]);
#pragma unroll
                        for (int j = 0; j < 4; ++j)
                            acc[i][j] = fmaf(af[kk], wf[j], acc[i][j]);
                    }
                }
            }
            // epilogue: u = (x - shift) * exp(-log_s); elem = -0.5u^2 - 0.5*log(2pi) - log_s
            const int j0 = cg3 * 2;
#pragma unroll
            for (int i = 0; i < 2; ++i) {
                const int row = rg3 + 16 * i;
                float p = 0.f;
#pragma unroll
                for (int jj = 0; jj < 2; ++jj) {
                    const int j = j0 + jj;
                    const float sh = acc[i][2 * jj];
                    const float ls = acc[i][2 * jj + 1];
                    const float x  = xgs[row * XG_S + j];
                    const float u  = (x - sh) * __expf(-ls);
                    p += (-0.5f * u * u - 0.91893853320467266954f - ls) * v_s[j];
                }
                red[row * 16 + cg3] = p;
            }
        }
        __syncthreads();

        // ---- reduce 16 partials per row, write ll ----
        if (tid < TROWS) {
            float s = 0.f;
#pragma unroll
            for (int m = 0; m < 16; ++m) s += red[tid * 16 + m];
            out[(row0 + tid) * RR + r] = s;
        }
        __syncthreads();
    }
}

extern "C" void kernel_launch(void* const* d_in, const int* in_sizes, int n_in,
                              void* d_out, int out_size, void* d_ws, size_t ws_size,
                              hipStream_t stream)
{
    const float* inputs = (const float*)d_in[0];
    const float* W1     = (const float*)d_in[1];
    const float* W2     = (const float*)d_in[2];
    const float* Wout   = (const float*)d_in[3];
    const int*   idx    = (const int*)d_in[4];
    const int*   valid  = (const int*)d_in[5];
    const int*   M1     = (const int*)d_in[6];
    const int*   M2     = (const int*)d_in[7];
    const int*   Mout   = (const int*)d_in[8];
    float*       out    = (float*)d_out;

    hipLaunchKernelGGL(made_flow_kernel, dim3(RR * BLOCKS_PER_R), dim3(256), 0, stream,
                       inputs, W1, W2, Wout, idx, valid, M1, M2, Mout, out);
}

// Round 2
// 223.919 us; speedup vs baseline: 1.7875x; 1.7875x over previous
//
#include <hip/hip_runtime.h>
#include <math.h>

// AutoregressiveFlowLayer on MI355X — round 2: split-bf16 MFMA (3-term: AhBh+AlBh+AhBl).
// R1 post-mortem: fp32 VALU version was LDS-read-bound (384 LDS cyc vs 128 FMA cyc per
// k-quad). MFMA gives 8 FLOP/LDS-byte. Split-bf16 keeps ~2^-16 relative error (absmax
// margin is 12x). Predicted ~75-95 us (from 360).

#define RR 32
#define DD 1024
#define HH 128
#define OO 64
#define TROWS 32
#define TILES_PER_BLOCK 16
#define BLOCKS_PER_R 16

#define S1 32    // bf16 k-stride for K=32 arrays (xg hi/lo, wt1): 64B rows -> bank-quad (4m+q)%8, balanced
#define S2 136   // bf16 k-stride for K=128 arrays (h1,h2,wt2,wto): 272B rows -> (m+q)%8, balanced
#define XS 36    // xg f32 row stride
#define OS 68    // outb f32 row stride

typedef short bf16x8_t __attribute__((ext_vector_type(8)));
typedef float f32x4_t __attribute__((ext_vector_type(4)));

__device__ __forceinline__ unsigned short bf16_rne(float x) {
    unsigned int u = __float_as_uint(x);
    u += 0x7FFFu + ((u >> 16) & 1u);
    return (unsigned short)(u >> 16);
}
__device__ __forceinline__ float bf16_tof(unsigned short h) {
    return __uint_as_float(((unsigned int)h) << 16);
}
__device__ __forceinline__ void split_store(float v, unsigned short* hi, unsigned short* lo, int off) {
    unsigned short h = bf16_rne(v);
    hi[off] = h;
    lo[off] = bf16_rne(v - bf16_tof(h));
}
__device__ __forceinline__ f32x4_t mfma16(bf16x8_t a, bf16x8_t b, f32x4_t c) {
    return __builtin_amdgcn_mfma_f32_16x16x32_bf16(a, b, c, 0, 0, 0);
}

__global__ __launch_bounds__(256, 1)
void made_flow_mfma(const float* __restrict__ inputs,
                    const float* __restrict__ W1,
                    const float* __restrict__ W2,
                    const float* __restrict__ Wout,
                    const int* __restrict__ idx,
                    const int* __restrict__ valid,
                    const int* __restrict__ M1,
                    const int* __restrict__ M2,
                    const int* __restrict__ Mout,
                    float* __restrict__ out)
{
    // Weight planes: [0]=hi, [1]=lo, stored transposed [col][k] (B-operand layout).
    __shared__ __align__(16) unsigned short wt1[2][HH * S1];   // 16 KB
    __shared__ __align__(16) unsigned short wt2[2][HH * S2];   // 68 KB
    __shared__ __align__(16) unsigned short wto[2][OO * S2];   // 34 KB
    // Region A: h1 hi/lo (phase1->2)  UNION  outb fp32 (phase3->epilogue)
    __shared__ __align__(16) char regA[2 * TROWS * S2 * 2];    // 17 KB
    // Region B: h2 hi/lo (phase2->3)  UNION  xg hi/lo (gather->phase1)
    __shared__ __align__(16) char regB[2 * TROWS * S2 * 2];    // 17 KB
    __shared__ float xgf[TROWS * XS];                          // 4.5 KB
    __shared__ int   idx_s[RR];
    __shared__ float v_s[RR];

    unsigned short* const h1h  = (unsigned short*)regA;
    unsigned short* const h1l  = h1h + TROWS * S2;
    float*          const outb = (float*)regA;
    unsigned short* const h2h  = (unsigned short*)regB;
    unsigned short* const h2l  = h2h + TROWS * S2;
    unsigned short* const xgh  = (unsigned short*)regB;
    unsigned short* const xgl  = xgh + TROWS * S1;

    const int tid  = threadIdx.x;
    const int r    = blockIdx.x / BLOCKS_PER_R;
    const int rb   = blockIdx.x % BLOCKS_PER_R;
    const int lane = tid & 63;
    const int wave = tid >> 6;
    const int q    = lane >> 4;   // quad: k-offset q*8 in frags
    const int l16  = lane & 15;   // m (A) / n (B) / col (C)

    // ---- stage masked, split weights, transposed to [col][k] ----
    {
        const float4* wv = (const float4*)(W1 + r * RR * HH);
        const int4*   mv = (const int4*)(M1 + r * RR * HH);
        for (int i = tid; i < RR * HH / 4; i += 256) {
            float4 w = wv[i]; int4 m = mv[i];
            const int k = (i * 4) >> 7, c = (i * 4) & 127;
            float e[4] = {m.x ? w.x : 0.f, m.y ? w.y : 0.f, m.z ? w.z : 0.f, m.w ? w.w : 0.f};
#pragma unroll
            for (int u = 0; u < 4; ++u)
                split_store(e[u], wt1[0], wt1[1], (c + u) * S1 + k);
        }
    }
    {
        const float4* wv = (const float4*)(W2 + r * HH * HH);
        const int4*   mv = (const int4*)(M2 + r * HH * HH);
        for (int i = tid; i < HH * HH / 4; i += 256) {
            float4 w = wv[i]; int4 m = mv[i];
            const int k = (i * 4) >> 7, c = (i * 4) & 127;
            float e[4] = {m.x ? w.x : 0.f, m.y ? w.y : 0.f, m.z ? w.z : 0.f, m.w ? w.w : 0.f};
#pragma unroll
            for (int u = 0; u < 4; ++u)
                split_store(e[u], wt2[0], wt2[1], (c + u) * S2 + k);
        }
    }
    {
        const float4* wv = (const float4*)(Wout + r * HH * OO);
        const int4*   mv = (const int4*)(Mout + r * HH * OO);
        for (int i = tid; i < HH * OO / 4; i += 256) {
            float4 w = wv[i]; int4 m = mv[i];
            const int k = (i * 4) >> 6, c = (i * 4) & 63;
            float e[4] = {m.x ? w.x : 0.f, m.y ? w.y : 0.f, m.z ? w.z : 0.f, m.w ? w.w : 0.f};
#pragma unroll
            for (int u = 0; u < 4; ++u)
                split_store(e[u], wto[0], wto[1], (c + u) * S2 + k);
        }
    }
    if (tid < RR) {
        idx_s[tid] = idx[r * RR + tid];
        v_s[tid]   = valid[r * RR + tid] ? 1.f : 0.f;
    }
    __syncthreads();

    const f32x4_t zero4 = {0.f, 0.f, 0.f, 0.f};

    for (int t = 0; t < TILES_PER_BLOCK; ++t) {
        const int row0 = (rb * TILES_PER_BLOCK + t) * TROWS;

        // ---- gather + split: xg fp32 (epilogue) + hi/lo (phase1 A-frags) ----
        {
            const int row  = tid >> 3;
            const int j0   = (tid & 7) * 4;
            const int base = (row0 + row) * DD;
#pragma unroll
            for (int u = 0; u < 4; ++u) {
                const int j = j0 + u;
                const float x = inputs[base + idx_s[j]] * v_s[j];
                xgf[row * XS + j] = x;
                split_store(x, xgh, xgl, row * S1 + j);
            }
        }
        __syncthreads();

        // ---- phase 1: h1 = relu(xg @ W1m)  M=32 N=128 K=32 ----
        {
            const int nb = 2 * wave; // this wave's n-tiles: nb, nb+1
            bf16x8_t ah[2], al[2], bh[2], bl[2];
#pragma unroll
            for (int mi = 0; mi < 2; ++mi) {
                ah[mi] = *(const bf16x8_t*)&xgh[(16 * mi + l16) * S1 + q * 8];
                al[mi] = *(const bf16x8_t*)&xgl[(16 * mi + l16) * S1 + q * 8];
            }
#pragma unroll
            for (int ni = 0; ni < 2; ++ni) {
                bh[ni] = *(const bf16x8_t*)&wt1[0][(16 * (nb + ni) + l16) * S1 + q * 8];
                bl[ni] = *(const bf16x8_t*)&wt1[1][(16 * (nb + ni) + l16) * S1 + q * 8];
            }
            f32x4_t acc[2][2];
#pragma unroll
            for (int mi = 0; mi < 2; ++mi)
#pragma unroll
                for (int ni = 0; ni < 2; ++ni) {
                    f32x4_t a = zero4;
                    a = mfma16(ah[mi], bh[ni], a);
                    a = mfma16(al[mi], bh[ni], a);
                    a = mfma16(ah[mi], bl[ni], a);
                    acc[mi][ni] = a;
                }
            __syncthreads(); // xg (regB) dead; h1 (regA) safe to write after all reads of outb-epoch done anyway
#pragma unroll
            for (int mi = 0; mi < 2; ++mi)
#pragma unroll
                for (int ni = 0; ni < 2; ++ni)
#pragma unroll
                    for (int i = 0; i < 4; ++i) {
                        const int rw = 16 * mi + 4 * q + i;
                        const int cl = 16 * (nb + ni) + l16;
                        split_store(fmaxf(acc[mi][ni][i], 0.f), h1h, h1l, rw * S2 + cl);
                    }
        }
        __syncthreads();

        // ---- phase 2: h2 = relu(h1 @ W2m)  M=32 N=128 K=128 ----
        {
            const int nb = 2 * wave;
            f32x4_t acc[2][2] = {{zero4, zero4}, {zero4, zero4}};
#pragma unroll
            for (int ks = 0; ks < 4; ++ks) {
                bf16x8_t ah[2], al[2], bh[2], bl[2];
#pragma unroll
                for (int mi = 0; mi < 2; ++mi) {
                    ah[mi] = *(const bf16x8_t*)&h1h[(16 * mi + l16) * S2 + ks * 32 + q * 8];
                    al[mi] = *(const bf16x8_t*)&h1l[(16 * mi + l16) * S2 + ks * 32 + q * 8];
                }
#pragma unroll
                for (int ni = 0; ni < 2; ++ni) {
                    bh[ni] = *(const bf16x8_t*)&wt2[0][(16 * (nb + ni) + l16) * S2 + ks * 32 + q * 8];
                    bl[ni] = *(const bf16x8_t*)&wt2[1][(16 * (nb + ni) + l16) * S2 + ks * 32 + q * 8];
                }
#pragma unroll
                for (int mi = 0; mi < 2; ++mi)
#pragma unroll
                    for (int ni = 0; ni < 2; ++ni) {
                        f32x4_t a = acc[mi][ni];
                        a = mfma16(ah[mi], bh[ni], a);
                        a = mfma16(al[mi], bh[ni], a);
                        a = mfma16(ah[mi], bl[ni], a);
                        acc[mi][ni] = a;
                    }
            }
            __syncthreads(); // all phase-2 reads of h1/wt2 done; h2 (regB) writes may now overlay xg
#pragma unroll
            for (int mi = 0; mi < 2; ++mi)
#pragma unroll
                for (int ni = 0; ni < 2; ++ni)
#pragma unroll
                    for (int i = 0; i < 4; ++i) {
                        const int rw = 16 * mi + 4 * q + i;
                        const int cl = 16 * (nb + ni) + l16;
                        split_store(fmaxf(acc[mi][ni][i], 0.f), h2h, h2l, rw * S2 + cl);
                    }
        }
        __syncthreads();

        // ---- phase 3: outb = h2 @ Woutm  M=32 N=64 K=128 ----
        {
            const int nt = wave; // cols 16*wave .. +15
            f32x4_t acc[2] = {zero4, zero4};
#pragma unroll
            for (int ks = 0; ks < 4; ++ks) {
                bf16x8_t ah[2], al[2], bh, bl;
#pragma unroll
                for (int mi = 0; mi < 2; ++mi) {
                    ah[mi] = *(const bf16x8_t*)&h2h[(16 * mi + l16) * S2 + ks * 32 + q * 8];
                    al[mi] = *(const bf16x8_t*)&h2l[(16 * mi + l16) * S2 + ks * 32 + q * 8];
                }
                bh = *(const bf16x8_t*)&wto[0][(16 * nt + l16) * S2 + ks * 32 + q * 8];
                bl = *(const bf16x8_t*)&wto[1][(16 * nt + l16) * S2 + ks * 32 + q * 8];
#pragma unroll
                for (int mi = 0; mi < 2; ++mi) {
                    f32x4_t a = acc[mi];
                    a = mfma16(ah[mi], bh, a);
                    a = mfma16(al[mi], bh, a);
                    a = mfma16(ah[mi], bl, a);
                    acc[mi] = a;
                }
            }
            __syncthreads(); // phase-2/3 reads of regA (h1) long done; outb writes overlay h1
#pragma unroll
            for (int mi = 0; mi < 2; ++mi)
#pragma unroll
                for (int i = 0; i < 4; ++i) {
                    const int rw = 16 * mi + 4 * q + i;
                    const int cl = 16 * nt + l16;
                    outb[rw * OS + cl] = acc[mi][i];
                }
        }
        __syncthreads();

        // ---- epilogue: ll = sum_j [ -0.5 u^2 - 0.5 log(2pi) - log_s ] * v ----
        {
            const int row = tid >> 3;   // 0..31
            const int g   = tid & 7;    // 4 j's per thread
            float p = 0.f;
#pragma unroll
            for (int jj = 0; jj < 4; ++jj) {
                const int j = g * 4 + jj;
                const float sh = outb[row * OS + 2 * j];
                const float ls = outb[row * OS + 2 * j + 1];
                const float x  = xgf[row * XS + j];
                const float uu = (x - sh) * __expf(-ls);
                p += (-0.5f * uu * uu - 0.91893853320467266954f - ls) * v_s[j];
            }
            p += __shfl_xor(p, 1);
            p += __shfl_xor(p, 2);
            p += __shfl_xor(p, 4);
            if (g == 0) out[(row0 + row) * RR + r] = p;
        }
        __syncthreads(); // xgf/outb reads done before next tile's gather/phase1 overwrite
    }
}

extern "C" void kernel_launch(void* const* d_in, const int* in_sizes, int n_in,
                              void* d_out, int out_size, void* d_ws, size_t ws_size,
                              hipStream_t stream)
{
    const float* inputs = (const float*)d_in[0];
    const float* W1     = (const float*)d_in[1];
    const float* W2     = (const float*)d_in[2];
    const float* Wout   = (const float*)d_in[3];
    const int*   idx    = (const int*)d_in[4];
    const int*   valid  = (const int*)d_in[5];
    const int*   M1     = (const int*)d_in[6];
    const int*   M2     = (const int*)d_in[7];
    const int*   Mout   = (const int*)d_in[8];
    float*       out    = (float*)d_out;

    hipLaunchKernelGGL(made_flow_mfma, dim3(RR * BLOCKS_PER_R), dim3(256), 0, stream,
                       inputs, W1, W2, Wout, idx, valid, M1, M2, Mout, out);
}

// Round 3
// 163.404 us; speedup vs baseline: 2.4494x; 1.3703x over previous
//
#include <hip/hip_runtime.h>
#include <math.h>

// AutoregressiveFlowLayer MI355X — round 3.
// R2 post-mortem: 154us, MfmaUtil 11.8%, 2.25e7 LDS bank conflict cycles (scalar u16
// split-stores = 4-way conflicts), 1 block/CU so barriers stall everything.
// R3: (1) W2/Wout B-frags in registers (96 VGPR/wave, staged once via chunked LDS
// scratch) -> LDS 157->58KB, steady-state LDS reads -45%; (2) 2 blocks/CU
// (__launch_bounds__(256,2)) to overlap barrier drains; (3) h-activations stored as
// packed (hi|lo<<16) dwords, stride 132 -> conflict-free b32 stores, b128 reads +
// v_perm unpack.

#define RR 32
#define DD 1024
#define HH 128
#define OO 64
#define TROWS 32
#define TILES_PER_BLOCK 16
#define BLOCKS_PER_R 16

#define SH  132   // packed h row stride (dwords): 528B rows, 16B aligned, 2-way store banks (free)
#define SXP 36    // packed xg row stride (dwords)
#define XS  36    // xgf f32 row stride
#define OS  68    // outb f32 row stride
#define SW  136   // weight scratch stride (ushorts): 272B rows, 16B aligned
#define SW1 40    // W1 plane stride (ushorts): 80B rows, 16B aligned

typedef short bf16x8_t __attribute__((ext_vector_type(8)));
typedef float f32x4_t __attribute__((ext_vector_type(4)));
typedef unsigned short u16;
typedef unsigned int u32;

__device__ __forceinline__ u16 bf16_rne(float x) {
    u32 u = __float_as_uint(x);
    u += 0x7FFFu + ((u >> 16) & 1u);
    return (u16)(u >> 16);
}
__device__ __forceinline__ float bf16_tof(u16 h) {
    return __uint_as_float(((u32)h) << 16);
}
__device__ __forceinline__ u32 pack_split(float v) {
    u16 h = bf16_rne(v);
    u16 l = bf16_rne(v - bf16_tof(h));
    return (u32)h | ((u32)l << 16);
}
__device__ __forceinline__ void split_store(float v, u16* hi, u16* lo, int off) {
    u16 h = bf16_rne(v);
    hi[off] = h;
    lo[off] = bf16_rne(v - bf16_tof(h));
}
// 8 packed dwords -> hi frag (8 bf16) + lo frag
__device__ __forceinline__ void unpack8(const u32* p, bf16x8_t& hi, bf16x8_t& lo) {
    uint4 a = *reinterpret_cast<const uint4*>(p);
    uint4 b = *reinterpret_cast<const uint4*>(p + 4);
    union { u32 u[4]; bf16x8_t v; } H, L;
    H.u[0] = __builtin_amdgcn_perm(a.y, a.x, 0x05040100u);
    H.u[1] = __builtin_amdgcn_perm(a.w, a.z, 0x05040100u);
    H.u[2] = __builtin_amdgcn_perm(b.y, b.x, 0x05040100u);
    H.u[3] = __builtin_amdgcn_perm(b.w, b.z, 0x05040100u);
    L.u[0] = __builtin_amdgcn_perm(a.y, a.x, 0x07060302u);
    L.u[1] = __builtin_amdgcn_perm(a.w, a.z, 0x07060302u);
    L.u[2] = __builtin_amdgcn_perm(b.y, b.x, 0x07060302u);
    L.u[3] = __builtin_amdgcn_perm(b.w, b.z, 0x07060302u);
    hi = H.v; lo = L.v;
}
__device__ __forceinline__ f32x4_t mfma16(bf16x8_t a, bf16x8_t b, f32x4_t c) {
    return __builtin_amdgcn_mfma_f32_16x16x32_bf16(a, b, c, 0, 0, 0);
}

__global__ __launch_bounds__(256, 2)
void made_flow_r3(const float* __restrict__ inputs,
                  const float* __restrict__ W1,
                  const float* __restrict__ W2,
                  const float* __restrict__ Wout,
                  const int* __restrict__ idx,
                  const int* __restrict__ valid,
                  const int* __restrict__ M1,
                  const int* __restrict__ M2,
                  const int* __restrict__ Mout,
                  float* __restrict__ out)
{
    // regA: h1 packed (32 x SH dwords, 16896B)  UNION  outb f32 (32 x OS)  UNION  W-scratch hi plane
    // regB: h2 packed                           UNION  xg packed           UNION  W-scratch lo plane
    __shared__ __align__(16) char regA[TROWS * SH * 4];
    __shared__ __align__(16) char regB[TROWS * SH * 4];
    __shared__ __align__(16) u16  w1hi[HH * SW1];   // 10 KB, persistent
    __shared__ __align__(16) u16  w1lo[HH * SW1];   // 10 KB, persistent
    __shared__ __align__(16) float xgf[TROWS * XS]; // 4.6 KB
    __shared__ int   idx_s[RR];
    __shared__ float v_s[RR];

    u32*   const h1p  = (u32*)regA;
    float* const outb = (float*)regA;
    u32*   const h2p  = (u32*)regB;
    u32*   const xgp  = (u32*)regB;
    u16*   const scrh = (u16*)regA;   // staging scratch (pre-loop only)
    u16*   const scrl = (u16*)regB;

    const int tid  = threadIdx.x;
    const int r    = blockIdx.x / BLOCKS_PER_R;
    const int rb   = blockIdx.x % BLOCKS_PER_R;
    const int lane = tid & 63;
    const int wave = tid >> 6;
    const int q    = lane >> 4;   // quad -> k-offset q*8 in frags / rows 4q+i in C
    const int l16  = lane & 15;

    if (tid < RR) {
        idx_s[tid] = idx[r * RR + tid];
        v_s[tid]   = valid[r * RR + tid] ? 1.f : 0.f;
    }

    // ---- stage W1 (persistent LDS planes, transposed [col][k]) ----
    {
        const float4* wv = (const float4*)(W1 + r * RR * HH);
        const int4*   mv = (const int4*)(M1 + r * RR * HH);
        for (int f = tid; f < RR * HH / 4; f += 256) {
            const int k = f >> 5, cg = f & 31;
            float4 w = wv[k * 32 + cg]; int4 m = mv[k * 32 + cg];
            float e[4] = {m.x ? w.x : 0.f, m.y ? w.y : 0.f, m.z ? w.z : 0.f, m.w ? w.w : 0.f};
#pragma unroll
            for (int u = 0; u < 4; ++u)
                split_store(e[u], w1hi, w1lo, (4 * cg + u) * SW1 + k);
        }
    }

    // ---- stage W2 -> per-wave register B-frags (4 chunks of 32 cols) ----
    bf16x8_t b2h[2][4], b2l[2][4];   // [ni][ks]
    bf16x8_t boh[4],    bol[4];      // [ks]
    {
        const float4* wv = (const float4*)(W2 + r * HH * HH);
        const int4*   mv = (const int4*)(M2 + r * HH * HH);
        for (int c = 0; c < 4; ++c) {
            __syncthreads();
            for (int f = tid; f < 1024; f += 256) {
                const int k = f >> 3, cg = f & 7;
                float4 w = wv[k * 32 + 8 * c + cg]; int4 m = mv[k * 32 + 8 * c + cg];
                float e[4] = {m.x ? w.x : 0.f, m.y ? w.y : 0.f, m.z ? w.z : 0.f, m.w ? w.w : 0.f};
#pragma unroll
                for (int u = 0; u < 4; ++u)
                    split_store(e[u], scrh, scrl, (4 * cg + u) * SW + k);
            }
            __syncthreads();
            if (wave == c) {
#pragma unroll
                for (int ni = 0; ni < 2; ++ni)
#pragma unroll
                    for (int ks = 0; ks < 4; ++ks) {
                        const int o = (16 * ni + l16) * SW + ks * 32 + q * 8;
                        b2h[ni][ks] = *(const bf16x8_t*)&scrh[o];
                        b2l[ni][ks] = *(const bf16x8_t*)&scrl[o];
                    }
            }
        }
    }
    // ---- stage Wout -> register B-frags (2 chunks of 32 cols) ----
    {
        const float4* wv = (const float4*)(Wout + r * HH * OO);
        const int4*   mv = (const int4*)(Mout + r * HH * OO);
        for (int c = 0; c < 2; ++c) {
            __syncthreads();
            for (int f = tid; f < 1024; f += 256) {
                const int k = f >> 3, cg = f & 7;
                float4 w = wv[k * 16 + 8 * c + cg]; int4 m = mv[k * 16 + 8 * c + cg];
                float e[4] = {m.x ? w.x : 0.f, m.y ? w.y : 0.f, m.z ? w.z : 0.f, m.w ? w.w : 0.f};
#pragma unroll
                for (int u = 0; u < 4; ++u)
                    split_store(e[u], scrh, scrl, (4 * cg + u) * SW + k);
            }
            __syncthreads();
            if ((wave >> 1) == c) {
                const int nl = wave & 1;
#pragma unroll
                for (int ks = 0; ks < 4; ++ks) {
                    const int o = (16 * nl + l16) * SW + ks * 32 + q * 8;
                    boh[ks] = *(const bf16x8_t*)&scrh[o];
                    bol[ks] = *(const bf16x8_t*)&scrl[o];
                }
            }
        }
    }
    __syncthreads();   // scratch readers done before main loop writes regA/regB

    const f32x4_t zero4 = {0.f, 0.f, 0.f, 0.f};

    for (int t = 0; t < TILES_PER_BLOCK; ++t) {
        const int row0 = (rb * TILES_PER_BLOCK + t) * TROWS;

        // ---- gather + pack ----
        {
            const int row  = tid >> 3;
            const int g    = tid & 7;
            const int base = (row0 + row) * DD;
            uint4 px; float4 fx;
            float x0 = inputs[base + idx_s[4 * g + 0]] * v_s[4 * g + 0];
            float x1 = inputs[base + idx_s[4 * g + 1]] * v_s[4 * g + 1];
            float x2 = inputs[base + idx_s[4 * g + 2]] * v_s[4 * g + 2];
            float x3 = inputs[base + idx_s[4 * g + 3]] * v_s[4 * g + 3];
            px.x = pack_split(x0); px.y = pack_split(x1);
            px.z = pack_split(x2); px.w = pack_split(x3);
            fx.x = x0; fx.y = x1; fx.z = x2; fx.w = x3;
            *(uint4*)&xgp[row * SXP + 4 * g]  = px;
            *(float4*)&xgf[row * XS + 4 * g]  = fx;
        }
        __syncthreads();

        // ---- phase 1: h1 = relu(xg @ W1m)  M=32 N=128 K=32 ----
        {
            const int nb = 2 * wave;
            bf16x8_t ah[2], al[2];
#pragma unroll
            for (int mi = 0; mi < 2; ++mi)
                unpack8(&xgp[(16 * mi + l16) * SXP + q * 8], ah[mi], al[mi]);
            f32x4_t acc[2][2];
#pragma unroll
            for (int ni = 0; ni < 2; ++ni) {
                const int o = (16 * (nb + ni) + l16) * SW1 + q * 8;
                bf16x8_t bh = *(const bf16x8_t*)&w1hi[o];
                bf16x8_t bl = *(const bf16x8_t*)&w1lo[o];
#pragma unroll
                for (int mi = 0; mi < 2; ++mi) {
                    f32x4_t a = zero4;
                    a = mfma16(ah[mi], bh, a);
                    a = mfma16(al[mi], bh, a);
                    a = mfma16(ah[mi], bl, a);
                    acc[mi][ni] = a;
                }
            }
#pragma unroll
            for (int mi = 0; mi < 2; ++mi)
#pragma unroll
                for (int ni = 0; ni < 2; ++ni)
#pragma unroll
                    for (int i = 0; i < 4; ++i)
                        h1p[(16 * mi + 4 * q + i) * SH + 16 * (nb + ni) + l16] =
                            pack_split(fmaxf(acc[mi][ni][i], 0.f));
        }
        __syncthreads();

        // ---- phase 2: h2 = relu(h1 @ W2m)  K=128, B-frags in registers ----
        {
            const int nb = 2 * wave;
            f32x4_t acc[2][2] = {{zero4, zero4}, {zero4, zero4}};
#pragma unroll
            for (int ks = 0; ks < 4; ++ks) {
#pragma unroll
                for (int mi = 0; mi < 2; ++mi) {
                    bf16x8_t ah, al;
                    unpack8(&h1p[(16 * mi + l16) * SH + ks * 32 + q * 8], ah, al);
#pragma unroll
                    for (int ni = 0; ni < 2; ++ni) {
                        f32x4_t a = acc[mi][ni];
                        a = mfma16(ah, b2h[ni][ks], a);
                        a = mfma16(al, b2h[ni][ks], a);
                        a = mfma16(ah, b2l[ni][ks], a);
                        acc[mi][ni] = a;
                    }
                }
            }
#pragma unroll
            for (int mi = 0; mi < 2; ++mi)
#pragma unroll
                for (int ni = 0; ni < 2; ++ni)
#pragma unroll
                    for (int i = 0; i < 4; ++i)
                        h2p[(16 * mi + 4 * q + i) * SH + 16 * (nb + ni) + l16] =
                            pack_split(fmaxf(acc[mi][ni][i], 0.f));
        }
        __syncthreads();

        // ---- phase 3: outb = h2 @ Woutm  N=64, B-frags in registers ----
        {
            f32x4_t acc[2] = {zero4, zero4};
#pragma unroll
            for (int ks = 0; ks < 4; ++ks) {
#pragma unroll
                for (int mi = 0; mi < 2; ++mi) {
                    bf16x8_t ah, al;
                    unpack8(&h2p[(16 * mi + l16) * SH + ks * 32 + q * 8], ah, al);
                    f32x4_t a = acc[mi];
                    a = mfma16(ah, boh[ks], a);
                    a = mfma16(al, boh[ks], a);
                    a = mfma16(ah, bol[ks], a);
                    acc[mi] = a;
                }
            }
#pragma unroll
            for (int mi = 0; mi < 2; ++mi)
#pragma unroll
                for (int i = 0; i < 4; ++i)
                    outb[(16 * mi + 4 * q + i) * OS + 16 * wave + l16] = acc[mi][i];
        }
        __syncthreads();

        // ---- epilogue ----
        {
            const int row = tid >> 3;
            const int g   = tid & 7;
            float4 o0 = *(const float4*)&outb[row * OS + 8 * g];
            float4 o1 = *(const float4*)&outb[row * OS + 8 * g + 4];
            float4 xv = *(const float4*)&xgf[row * XS + 4 * g];
            float p = 0.f;
            {
                float u0 = (xv.x - o0.x) * __expf(-o0.y);
                float u1 = (xv.y - o0.z) * __expf(-o0.w);
                float u2 = (xv.z - o1.x) * __expf(-o1.y);
                float u3 = (xv.w - o1.z) * __expf(-o1.w);
                p += (-0.5f * u0 * u0 - 0.91893853320467266954f - o0.y) * v_s[4 * g + 0];
                p += (-0.5f * u1 * u1 - 0.91893853320467266954f - o0.w) * v_s[4 * g + 1];
                p += (-0.5f * u2 * u2 - 0.91893853320467266954f - o1.y) * v_s[4 * g + 2];
                p += (-0.5f * u3 * u3 - 0.91893853320467266954f - o1.w) * v_s[4 * g + 3];
            }
            p += __shfl_xor(p, 1);
            p += __shfl_xor(p, 2);
            p += __shfl_xor(p, 4);
            if (g == 0) out[(row0 + row) * RR + r] = p;
        }
        __syncthreads();
    }
}

extern "C" void kernel_launch(void* const* d_in, const int* in_sizes, int n_in,
                              void* d_out, int out_size, void* d_ws, size_t ws_size,
                              hipStream_t stream)
{
    const float* inputs = (const float*)d_in[0];
    const float* W1     = (const float*)d_in[1];
    const float* W2     = (const float*)d_in[2];
    const float* Wout   = (const float*)d_in[3];
    const int*   idx    = (const int*)d_in[4];
    const int*   valid  = (const int*)d_in[5];
    const int*   M1     = (const int*)d_in[6];
    const int*   M2     = (const int*)d_in[7];
    const int*   Mout   = (const int*)d_in[8];
    float*       out    = (float*)d_out;

    hipLaunchKernelGGL(made_flow_r3, dim3(RR * BLOCKS_PER_R), dim3(256), 0, stream,
                       inputs, W1, W2, Wout, idx, valid, M1, M2, Mout, out);
}